// Round 1
// 516.989 us; speedup vs baseline: 1.0570x; 1.0570x over previous
//
#include <hip/hip_runtime.h>
#include <math.h>

#define NB 512
#define NH 1024
#define NS 1024
#define ND 128
#define NK 32

typedef float fx4 __attribute__((ext_vector_type(4)));

// Fused kernel: per-batch compute with the streaming memory->out_mem copy
// woven through the compute phases (loads at phase start, stores at phase
// end, inside each barrier interval), then a sparse 32-row blend fixup.
__global__ __launch_bounds__(512, 4) void fused_kernel(
    const float* __restrict__ latent,      // [B,H]
    const float* __restrict__ memory,      // [B,S,D]
    const float* __restrict__ rq_w,        // [H,D]
    const float* __restrict__ rq_b,        // [D]
    const float* __restrict__ mem_key,     // [S,D]
    const float* __restrict__ wg_w,        // [H+D]
    const float* __restrict__ wg_b,        // [1]
    const float* __restrict__ dmd_w,       // [H+D]
    const float* __restrict__ dmd_b,       // [1]
    const float* __restrict__ ph_w,        // [H]
    const float* __restrict__ ph_b,        // [1]
    const float* __restrict__ wv_w,        // [H,D]
    const float* __restrict__ wv_b,        // [D]
    float* __restrict__ out_read,          // [B,D]
    float* __restrict__ out_mem,           // [B,S,D]
    float* __restrict__ out_wts)           // [B,S]
{
  const int b    = blockIdx.x;
  const int tid  = threadIdx.x;
  const int lane = tid & 63;
  const int wv   = tid >> 6;               // wave id, 0..7

  __shared__ float lat[NH];                // 4 KB
  __shared__ float wfull[NS];              // 4 KB
  __shared__ float part[512];              // 2 KB
  __shared__ __align__(16) float qv[ND];
  __shared__ float rd[ND];
  __shared__ float tvw[256];               // 8 waves x 32 candidates
  __shared__ int   tiw[256];
  __shared__ float wkL[NK];
  __shared__ int   tiL[NK];
  __shared__ __align__(16) float valw_s[ND];
  __shared__ float gred[24];
  __shared__ float scal[1];

  // block's 512 KB slice of memory: 32768 float4, 64 stripes of 512 f4
  const fx4* __restrict__ msrc = (const fx4*)memory + (size_t)b * (NS * ND / 4);
  fx4*       __restrict__ mdst = (fx4*)out_mem      + (size_t)b * (NS * ND / 4);
  fx4 buf[8];
  int cur = 0;                             // stripe cursor, 0..64

#define CK_LOAD(N)  { _Pragma("unroll") \
    for (int j = 0; j < (N); ++j) \
      buf[j] = __builtin_nontemporal_load(msrc + (size_t)(cur + j) * 512 + tid); }
#define CK_STORE(N) { _Pragma("unroll") \
    for (int j = 0; j < (N); ++j) \
      __builtin_nontemporal_store(buf[j], mdst + (size_t)(cur + j) * 512 + tid); \
    cur += (N); }

  // ---- A: latent row into LDS ---- (+copy stripes 0..7)
  CK_LOAD(8);
  lat[tid]       = latent[(size_t)b * NH + tid];
  lat[tid + 512] = latent[(size_t)b * NH + tid + 512];
  CK_STORE(8);
  __syncthreads();

  // ---- B: query = lat @ rq_w (split-4 over H) ---- (+4 stripes)
  CK_LOAD(4);
  {
    const int d = tid & 127, p = tid >> 7;
    const float* W = rq_w + (size_t)(p * 256) * ND + d;
    const float* L = lat + p * 256;
    float acc = 0.f;
    #pragma unroll 8
    for (int h = 0; h < 256; ++h) acc = fmaf(L[h], W[(size_t)h * ND], acc);
    part[tid] = acc;
  }
  CK_STORE(4);
  __syncthreads();

  // ---- qv reduce (mostly idle -> big copy chunk) ---- (+8 stripes)
  CK_LOAD(8);
  if (tid < ND)
    qv[tid] = part[tid] + part[tid + 128] + part[tid + 256] + part[tid + 384] + rq_b[tid];
  CK_STORE(8);
  __syncthreads();

  // ---- D: logits, 2 slots per thread, kept in regs ---- (+4 stripes)
  float r0 = 0.f, r1 = 0.f;
  CK_LOAD(4);
  {
    const float4* q4 = (const float4*)qv;
    const float4* k0 = (const float4*)(mem_key + (size_t)tid * ND);
    const float4* k1 = (const float4*)(mem_key + (size_t)(tid + 512) * ND);
    #pragma unroll 8
    for (int i = 0; i < ND / 4; ++i) {
      float4 q = q4[i];
      float4 x = k0[i];
      float4 y = k1[i];
      r0 += q.x * x.x + q.y * x.y + q.z * x.z + q.w * x.w;
      r1 += q.x * y.x + q.y * y.y + q.z * y.z + q.w * y.w;
    }
  }
  CK_STORE(4);

  // ---- E: per-wave top-32 via register/shuffle argmax ---- (+4 stripes)
  const float NEGINF = -3.0e38f;
  float selv = NEGINF; int seli = -1; float wkreg = 0.f;
  CK_LOAD(4);
  {
    const int s0 = tid, s1 = tid + 512;
    float v0 = r0, v1 = r1;
    for (int kk = 0; kk < NK; ++kk) {
      float best; int bi;
      if (v0 >= v1) { best = v0; bi = s0; } else { best = v1; bi = s1; }
      #pragma unroll
      for (int off = 1; off < 64; off <<= 1) {
        float ov = __shfl_xor(best, off);
        int   oi = __shfl_xor(bi, off);
        if (ov > best || (ov == best && oi < bi)) { best = ov; bi = oi; }
      }
      if (lane == 0) { tvw[(wv << 5) + kk] = best; tiw[(wv << 5) + kk] = bi; }
      if (bi == s0) v0 = NEGINF;
      if (bi == s1) v1 = NEGINF;
    }
  }
  wfull[tid] = 0.f; wfull[tid + 512] = 0.f;
  CK_STORE(4);
  __syncthreads();

  // ---- F: wave 0 merges 8x32 lists; waves 1-7 just stream copy ---- (+8)
  CK_LOAD(8);
  if (wv == 0) {
    float m0 = tvw[lane], m1 = tvw[lane + 64], m2 = tvw[lane + 128], m3 = tvw[lane + 192];
    int   i0 = tiw[lane], i1 = tiw[lane + 64], i2 = tiw[lane + 128], i3 = tiw[lane + 192];
    for (int kk = 0; kk < NK; ++kk) {
      float best = m0; int bi = i0;
      if (m1 > best || (m1 == best && i1 < bi)) { best = m1; bi = i1; }
      if (m2 > best || (m2 == best && i2 < bi)) { best = m2; bi = i2; }
      if (m3 > best || (m3 == best && i3 < bi)) { best = m3; bi = i3; }
      #pragma unroll
      for (int off = 1; off < 64; off <<= 1) {
        float ov = __shfl_xor(best, off);
        int   oi = __shfl_xor(bi, off);
        if (ov > best || (ov == best && oi < bi)) { best = ov; bi = oi; }
      }
      if (kk == lane) { selv = best; seli = bi; }
      if (bi == i0) m0 = NEGINF;
      if (bi == i1) m1 = NEGINF;
      if (bi == i2) m2 = NEGINF;
      if (bi == i3) m3 = NEGINF;
    }
    float maxv = __shfl(selv, 0);
    float e = (lane < NK) ? expf(selv - maxv) : 0.f;
    float s = e;
    #pragma unroll
    for (int off = 1; off < 64; off <<= 1) s += __shfl_xor(s, off);
    wkreg = e / s;
    if (lane < NK) { wkL[lane] = wkreg; tiL[lane] = seli; }
  }
  CK_STORE(8);
  __syncthreads();

  // ---- G: scatter weights into wfull; gather read (split-4 over k) ---- (+4)
  if (wv == 0 && lane < NK) wfull[seli] = wkreg;
  CK_LOAD(4);
  {
    const int d = tid & 127, p = tid >> 7;
    const float* mb = memory + (size_t)b * NS * ND;
    float racc = 0.f;
    #pragma unroll
    for (int k = p * 8; k < p * 8 + 8; ++k)
      racc = fmaf(wkL[k], mb[(size_t)tiL[k] * ND + d], racc);
    part[tid] = racc;
  }
  CK_STORE(4);
  __syncthreads();

  // ---- rd reduce (mostly idle -> big copy chunk) ---- (+8)
  CK_LOAD(8);
  if (tid < ND) {
    float r = part[tid] + part[tid + 128] + part[tid + 256] + part[tid + 384];
    rd[tid] = r;
    out_read[(size_t)b * ND + tid] = r;
  }
  CK_STORE(8);
  __syncthreads();

  // ---- I1: gate dot partials + value GEMV partials ---- (+4)
  CK_LOAD(4);
  {
    float l0 = lat[tid], l1 = lat[tid + 512];
    float p1 = l0 * wg_w[tid]  + l1 * wg_w[tid + 512];
    float p2 = l0 * dmd_w[tid] + l1 * dmd_w[tid + 512];
    float p3 = l0 * ph_w[tid]  + l1 * ph_w[tid + 512];
    if (tid < ND) {
      float r = rd[tid];
      p1 += r * wg_w[NH + tid];
      p2 += r * dmd_w[NH + tid];
    }
    #pragma unroll
    for (int off = 1; off < 64; off <<= 1) {
      p1 += __shfl_xor(p1, off);
      p2 += __shfl_xor(p2, off);
      p3 += __shfl_xor(p3, off);
    }
    if (lane == 0) { gred[wv] = p1; gred[8 + wv] = p2; gred[16 + wv] = p3; }
  }
  {
    const int d = tid & 127, p = tid >> 7;
    const float* W = wv_w + (size_t)(p * 256) * ND + d;
    const float* L = lat + p * 256;
    float acc = 0.f;
    #pragma unroll 8
    for (int h = 0; h < 256; ++h) acc = fmaf(L[h], W[(size_t)h * ND], acc);
    part[tid] = acc;
  }
  CK_STORE(4);
  __syncthreads();

  // ---- I2: gate scalar (1 thread; others stream copy) ---- (+6)
  CK_LOAD(6);
  if (tid == 0) {
    float z1 = wg_b[0], z2 = dmd_b[0], z3 = ph_b[0];
    #pragma unroll
    for (int k = 0; k < 8; ++k) { z1 += gred[k]; z2 += gred[8 + k]; z3 += gred[16 + k]; }
    float g  = 1.f / (1.f + expf(-z1));
    float dm = tanhf(z2);
    g = g * (0.75f + 0.25f * (dm + 1.f));
    g = fminf(fmaxf(g, 0.f), 1.f);
    g = g * (0.5f * (1.f + cosf(z3)));
    scal[0] = g;
  }
  CK_STORE(6);
  __syncthreads();

  // ---- J: weights output + value vector into LDS ---- (+6, completes 64)
  CK_LOAD(6);
  {
    float w0 = wfull[tid], w1 = wfull[tid + 512];
    out_wts[(size_t)b * NS + tid]       = w0;
    out_wts[(size_t)b * NS + tid + 512] = w1;
    if (tid < ND)
      valw_s[tid] = part[tid] + part[tid + 128] + part[tid + 256] + part[tid + 384] + wv_b[tid];
  }
  CK_STORE(6);
  __syncthreads();   // all copy stores drained; scal/wkL/tiL/valw_s visible

  // ---- K: fixup the 32 selected rows: out = (1-g*w)*m + g*w*value ----
  {
    const float g = scal[0];
    const fx4* v4 = (const fx4*)valw_s;
    #pragma unroll
    for (int u = 0; u < 2; ++u) {
      const int idx = tid + u * 512;        // 0..1023 = 32 rows x 32 f4
      const int k   = idx >> 5;
      const int c   = idx & 31;
      const float w = g * wkL[k];
      const int row = tiL[k];
      const fx4 m = msrc[(size_t)row * 32 + c];
      __builtin_nontemporal_store((1.f - w) * m + w * v4[c],
                                  mdst + (size_t)row * 32 + c);
    }
  }
#undef CK_LOAD
#undef CK_STORE
}

extern "C" void kernel_launch(void* const* d_in, const int* in_sizes, int n_in,
                              void* d_out, int out_size, void* d_ws, size_t ws_size,
                              hipStream_t stream) {
  const float* latent  = (const float*)d_in[0];
  const float* memory  = (const float*)d_in[1];
  const float* rq_w    = (const float*)d_in[2];
  const float* rq_b    = (const float*)d_in[3];
  const float* mem_key = (const float*)d_in[4];
  const float* wg_w    = (const float*)d_in[5];
  const float* wg_b    = (const float*)d_in[6];
  const float* dmd_w   = (const float*)d_in[7];
  const float* dmd_b   = (const float*)d_in[8];
  const float* ph_w    = (const float*)d_in[9];
  const float* ph_b    = (const float*)d_in[10];
  const float* wv_w    = (const float*)d_in[11];
  const float* wv_b    = (const float*)d_in[12];

  float* out_read = (float*)d_out;                          // [B,D]
  float* out_mem  = out_read + (size_t)NB * ND;             // [B,S,D]
  float* out_wts  = out_mem + (size_t)NB * NS * ND;         // [B,S]

  fused_kernel<<<NB, 512, 0, stream>>>(
      latent, memory, rq_w, rq_b, mem_key, wg_w, wg_b, dmd_w, dmd_b,
      ph_w, ph_b, wv_w, wv_b, out_read, out_mem, out_wts);
}